// Round 4
// baseline (278.998 us; speedup 1.0000x reference)
//
#include <hip/hip_runtime.h>
#include <hip/hip_bf16.h>

#define S_LEN 4096
#define NH 4
#define HD 256
#define WIN 512
#define ATT_SCALE 0.0625f   // 256^-0.5
#define QKV_N 1536          // packed q(1024) | k(256) | v(256)

typedef short s16x8 __attribute__((ext_vector_type(8)));
typedef float f32x4 __attribute__((ext_vector_type(4)));

static __device__ inline unsigned short f2bf(float f) {
  union { float f; unsigned int u; } v; v.f = f;
  unsigned int r = v.u + 0x7fff + ((v.u >> 16) & 1);   // RNE
  return (unsigned short)(r >> 16);
}
static __device__ inline float bf2f(unsigned short h) {
  union { unsigned int u; float f; } v; v.u = ((unsigned int)h) << 16;
  return v.f;
}
static __device__ inline void gl2lds16(const void* g, void* l) {
  __builtin_amdgcn_global_load_lds(
      (const __attribute__((address_space(1))) unsigned int*)g,
      (__attribute__((address_space(3))) unsigned int*)l, 16, 0, 0);
}

// ---------------------------------------------------------------------------
// x (fp32) -> bf16, packed uint2 stores. n4 = n/4.
// ---------------------------------------------------------------------------
__global__ __launch_bounds__(256) void cvt_bf16_kernel(const float* __restrict__ src,
                                                       unsigned short* __restrict__ dst,
                                                       int n4) {
  const int t = blockIdx.x * 256 + threadIdx.x;
  if (t >= n4) return;
  const float4 v = ((const float4*)src)[t];
  const unsigned int p0 = f2bf(v.x) | ((unsigned int)f2bf(v.y) << 16);
  const unsigned int p1 = f2bf(v.z) | ((unsigned int)f2bf(v.w) << 16);
  *(uint2*)(dst + (size_t)t * 4) = make_uint2(p0, p1);
}

// ---------------------------------------------------------------------------
// Transpose + cast: dst[n*K + k] = bf16(src[k*N + n]).  K,N multiples of 64.
// ---------------------------------------------------------------------------
__global__ __launch_bounds__(256) void trcast64_kernel(const float* __restrict__ src,
                                                       unsigned short* __restrict__ dst,
                                                       int K, int N) {
  __shared__ float ts[64][65];
  const int bn = blockIdx.x, bk = blockIdx.y;
  const int tid = threadIdx.x;
#pragma unroll
  for (int it = 0; it < 4; ++it) {
    const int c = it * 256 + tid;
    const int row = c >> 4, col4 = (c & 15) << 2;
    const float4 v = *(const float4*)(src + (size_t)(bk * 64 + row) * N + bn * 64 + col4);
    ts[row][col4 + 0] = v.x; ts[row][col4 + 1] = v.y;
    ts[row][col4 + 2] = v.z; ts[row][col4 + 3] = v.w;
  }
  __syncthreads();
#pragma unroll
  for (int it = 0; it < 4; ++it) {
    const int c = it * 256 + tid;
    const int nrow = c >> 4, kc4 = (c & 15) << 2;
    const unsigned int p0 = f2bf(ts[kc4 + 0][nrow]) | ((unsigned int)f2bf(ts[kc4 + 1][nrow]) << 16);
    const unsigned int p1 = f2bf(ts[kc4 + 2][nrow]) | ((unsigned int)f2bf(ts[kc4 + 3][nrow]) << 16);
    *(uint2*)(dst + (size_t)(bn * 64 + nrow) * K + bk * 64 + kc4) = make_uint2(p0, p1);
  }
}

// ---------------------------------------------------------------------------
// bf16 MFMA GEMM (m97 structure): C[M,N] = A[M,K] @ Bt[N,K]^T.
// ---------------------------------------------------------------------------
template <bool BF16OUT>
__global__ __launch_bounds__(256) void gemm_bt(const unsigned short* __restrict__ A,
                                               const unsigned short* __restrict__ Bt,
                                               void* __restrict__ Cv,
                                               int M, int N, int K) {
  __shared__ unsigned short As[128 * 32];
  __shared__ unsigned short Bs[128 * 32];
  const int tid = threadIdx.x;
  const int wave = tid >> 6, lane = tid & 63;
  const int ln15 = lane & 15, lgr = lane >> 4;
  const int bm = blockIdx.y, bn = blockIdx.x;
  const int wr = wave & 1, wc = wave >> 1;
  const unsigned short* Ab = A + (size_t)bm * 128 * K;
  const unsigned short* Bb = Bt + (size_t)bn * 128 * K;

  f32x4 acc[4][4];
#pragma unroll
  for (int mt = 0; mt < 4; ++mt)
#pragma unroll
    for (int nt = 0; nt < 4; ++nt) acc[mt][nt] = (f32x4){0.f, 0.f, 0.f, 0.f};

  for (int kt = 0; kt < K; kt += 32) {
#pragma unroll
    for (int i = 0; i < 2; ++i) {
      const int c = tid + 256 * i;
      const int row = c >> 2, kc = (c & 3) << 3;
      gl2lds16(Ab + (size_t)row * K + kt + kc, &As[c * 8]);
      gl2lds16(Bb + (size_t)row * K + kt + kc, &Bs[c * 8]);
    }
    __syncthreads();
    s16x8 af[4], bfr[4];
#pragma unroll
    for (int t = 0; t < 4; ++t) {
      af[t]  = *(const s16x8*)&As[(wr * 64 + t * 16 + ln15) * 32 + lgr * 8];
      bfr[t] = *(const s16x8*)&Bs[(wc * 64 + t * 16 + ln15) * 32 + lgr * 8];
    }
#pragma unroll
    for (int mt = 0; mt < 4; ++mt)
#pragma unroll
      for (int nt = 0; nt < 4; ++nt)
        acc[mt][nt] = __builtin_amdgcn_mfma_f32_16x16x32_bf16(af[mt], bfr[nt], acc[mt][nt], 0, 0, 0);
    __syncthreads();
  }

#pragma unroll
  for (int mt = 0; mt < 4; ++mt)
#pragma unroll
    for (int nt = 0; nt < 4; ++nt)
#pragma unroll
      for (int r = 0; r < 4; ++r) {
        const size_t row = bm * 128 + wr * 64 + mt * 16 + lgr * 4 + r;
        const size_t col = bn * 128 + wc * 64 + nt * 16 + ln15;
        if (BF16OUT) ((unsigned short*)Cv)[row * N + col] = f2bf(acc[mt][nt][r]);
        else         ((float*)Cv)[row * N + col] = acc[mt][nt][r];
      }
}

// ---------------------------------------------------------------------------
// Fused RMSNorm + RoPE, in place on packed bf16 qkv (row stride 1536).
// ---------------------------------------------------------------------------
__global__ __launch_bounds__(256) void normrope_kernel(
    unsigned short* __restrict__ qkv,
    const float* __restrict__ cosb, const float* __restrict__ sinb,
    const float* __restrict__ qw, const float* __restrict__ kw) {
  const int idx = blockIdx.x;
  const int h = idx % 5;
  const int bs = idx / 5;
  const int s = bs & (S_LEN - 1);
  unsigned short* base = qkv + (size_t)bs * QKV_N;
  unsigned short* row; const float* w; float oscale;
  if (h < 4) { row = base + h * HD;  w = qw; oscale = ATT_SCALE; }
  else       { row = base + 4 * HD;  w = kw; oscale = 1.0f; }
  const int tid = threadIdx.x;
  const int lane = tid & 63, wave = tid >> 6;
  __shared__ float xs[HD];
  __shared__ float red[4];
  const float xv = bf2f(row[tid]);
  xs[tid] = xv;
  float ssq = xv * xv;
#pragma unroll
  for (int off = 32; off > 0; off >>= 1) ssq += __shfl_xor(ssq, off);
  if (lane == 0) red[wave] = ssq;
  __syncthreads();
  const float tot = red[0] + red[1] + red[2] + red[3];
  const float inv = rsqrtf(tot * (1.0f / 256.0f) + 1e-6f);
  const int pi = tid >> 1;
  const float c = cosb[s * (HD / 2) + pi];
  const float sn = sinb[s * (HD / 2) + pi];
  const float a = xs[pi * 2]     * inv * (1.0f + w[pi * 2]);
  const float b = xs[pi * 2 + 1] * inv * (1.0f + w[pi * 2 + 1]);
  const float outv = ((tid & 1) ? (a * sn + b * c) : (a * c - b * sn)) * oscale;
  row[tid] = f2bf(outv);
}

// ---------------------------------------------------------------------------
// V transpose, tile-blocked: vtb[b][jt][d][jj] = v[b][jt*32+jj][d] (bf16)
// ---------------------------------------------------------------------------
__global__ __launch_bounds__(256) void vtranspose_kernel(
    const unsigned short* __restrict__ qkv, unsigned short* __restrict__ vtb) {
  __shared__ unsigned short ts[32][264];
  const int b = blockIdx.x >> 7, jt = blockIdx.x & 127;
  const int tid = threadIdx.x;
  const unsigned short* src = qkv + ((size_t)(b * S_LEN) + jt * 32) * QKV_N + 5 * HD;
#pragma unroll
  for (int it = 0; it < 4; ++it) {
    const int c = tid + 256 * it;
    const int row = c >> 5, col8 = (c & 31) << 3;
    *(uint4*)&ts[row][col8] = *(const uint4*)(src + (size_t)row * QKV_N + col8);
  }
  __syncthreads();
  unsigned short tmp[32];
#pragma unroll
  for (int jj = 0; jj < 32; ++jj) tmp[jj] = ts[jj][tid];
  unsigned short* dst = vtb + ((size_t)(b * 128 + jt) * 256 + tid) * 32;
#pragma unroll
  for (int wq = 0; wq < 4; ++wq) *(uint4*)(dst + wq * 8) = *(uint4*)(tmp + wq * 8);
}

// ---------------------------------------------------------------------------
// Flash-style sliding-window MQA, bf16 MFMA.
// XCD-swizzled: xcd = blockIdx&7 owns q-tile band [xcd*16, xcd*16+16) x 4 heads
// (K/V band = 1.5 MB, fits per-XCD L2; all 64 blocks of an XCD co-resident).
// Static-max softmax: RMSNorm => |q.k|*scale <= 16 exactly, so m == 16 fixed;
// no online max / rescale; l reduced once after the loop.
// Double-buffered K/V staging; one barrier per kt.
// ---------------------------------------------------------------------------
#define KS_LD 264
#define VT_LD 40
#define PS_LD 40

__global__ __launch_bounds__(256) void attn_mfma_kernel(
    const unsigned short* __restrict__ qkv, const unsigned short* __restrict__ vtb,
    unsigned short* __restrict__ aob) {
  const int g = blockIdx.x;
  const int xcd = g & 7, slot = g >> 3;      // assume block j -> XCD j%8
  const int h = slot >> 4;                   // 0..3
  const int qt = xcd * 16 + (slot & 15);     // 0..127
  const int b = qt >> 6;
  const int q0 = (qt & 63) << 6;
  const int tid = threadIdx.x;
  const int wave = tid >> 6;
  const int lane = tid & 63;
  const int ln15 = lane & 15;
  const int lgr = lane >> 4;

  __shared__ unsigned short Ks[2][32 * KS_LD];
  __shared__ unsigned short Vts[2][256 * VT_LD];
  __shared__ unsigned short Ps[4][16 * PS_LD];

  const size_t qrow = (size_t)(b * S_LEN + q0 + wave * 16 + ln15) * QKV_N + h * HD;
  s16x8 qfrag[8];
#pragma unroll
  for (int f = 0; f < 8; ++f)
    qfrag[f] = *(const s16x8*)(qkv + qrow + f * 32 + lgr * 8);

  f32x4 acc[16];
#pragma unroll
  for (int t = 0; t < 16; ++t) acc[t] = (f32x4){0.f, 0.f, 0.f, 0.f};
  float l_part[4] = {0.f, 0.f, 0.f, 0.f};

  const int kt_lo = max(0, q0 - WIN) >> 5;
  const int kt_hi = (q0 + 63) >> 5;
  const unsigned short* kbase = qkv + (size_t)(b * S_LEN) * QKV_N + 4 * HD;
  const unsigned short* vbase = vtb + (size_t)b * (S_LEN / 32) * HD * 32;

  uint4 stk[4], stv[4];
  auto load_tile = [&](int kt) {
    const unsigned short* src = kbase + (size_t)kt * 32 * QKV_N;
#pragma unroll
    for (int it = 0; it < 4; ++it) {
      const int c = tid + 256 * it;
      stk[it] = *(const uint4*)(src + (size_t)(c >> 5) * QKV_N + ((c & 31) << 3));
    }
    const unsigned short* vsrc = vbase + (size_t)kt * HD * 32;
#pragma unroll
    for (int it = 0; it < 4; ++it) {
      const int c = tid + 256 * it;
      stv[it] = *(const uint4*)(vsrc + (size_t)c * 8);
    }
  };
  auto write_tile = [&](int buf) {
#pragma unroll
    for (int it = 0; it < 4; ++it) {
      const int c = tid + 256 * it;
      *(uint4*)&Ks[buf][(c >> 5) * KS_LD + ((c & 31) << 3)] = stk[it];
      *(uint4*)&Vts[buf][(c >> 2) * VT_LD + ((c & 3) << 3)] = stv[it];
    }
  };

  load_tile(kt_lo);
  write_tile(0);
  __syncthreads();

  unsigned short* psw = Ps[wave];
  const int i_row0 = q0 + wave * 16 + lgr * 4;

  for (int kt = kt_lo; kt <= kt_hi; ++kt) {
    const int cur = (kt - kt_lo) & 1;
    if (kt < kt_hi) load_tile(kt + 1);   // global loads overlap compute

    // QK^T
    f32x4 sc[2];
    sc[0] = (f32x4){0.f, 0.f, 0.f, 0.f};
    sc[1] = (f32x4){0.f, 0.f, 0.f, 0.f};
#pragma unroll
    for (int f = 0; f < 8; ++f) {
#pragma unroll
      for (int ct = 0; ct < 2; ++ct) {
        const s16x8 kf = *(const s16x8*)&Ks[cur][(ct * 16 + ln15) * KS_LD + f * 32 + lgr * 8];
        sc[ct] = __builtin_amdgcn_mfma_f32_16x16x32_bf16(qfrag[f], kf, sc[ct], 0, 0, 0);
      }
    }

    // static-max softmax: p = exp(s - 16), masked to 0
    const int j0 = kt * 32 + ln15;
    float p0[4], p1[4];
#pragma unroll
    for (int r = 0; r < 4; ++r) {
      const int i = i_row0 + r;
      const bool a0 = (j0 <= i) && (i - j0 <= WIN);
      const bool a1 = (j0 + 16 <= i) && (i - (j0 + 16) <= WIN);
      const float e0 = __expf(sc[0][r] - 16.0f);
      const float e1 = __expf(sc[1][r] - 16.0f);
      p0[r] = a0 ? e0 : 0.0f;
      p1[r] = a1 ? e1 : 0.0f;
      l_part[r] += p0[r] + p1[r];
    }
#pragma unroll
    for (int r = 0; r < 4; ++r) {
      psw[(lgr * 4 + r) * PS_LD + ln15]      = f2bf(p0[r]);
      psw[(lgr * 4 + r) * PS_LD + 16 + ln15] = f2bf(p1[r]);
    }
    // wave-private P: in-wave lgkmcnt ordering suffices, no barrier
    const s16x8 pf = *(const s16x8*)&psw[ln15 * PS_LD + lgr * 8];
#pragma unroll
    for (int t = 0; t < 16; ++t) {
      const s16x8 vf = *(const s16x8*)&Vts[cur][(t * 16 + ln15) * VT_LD + lgr * 8];
      acc[t] = __builtin_amdgcn_mfma_f32_16x16x32_bf16(pf, vf, acc[t], 0, 0, 0);
    }

    if (kt < kt_hi) write_tile(cur ^ 1);
    __syncthreads();
  }

  // reduce l across the 16 lanes of each row group
#pragma unroll
  for (int off = 1; off < 16; off <<= 1)
#pragma unroll
    for (int r = 0; r < 4; ++r) l_part[r] += __shfl_xor(l_part[r], off);

  float inv_l[4];
#pragma unroll
  for (int r = 0; r < 4; ++r) inv_l[r] = 1.0f / l_part[r];
#pragma unroll
  for (int t = 0; t < 16; ++t)
#pragma unroll
    for (int r = 0; r < 4; ++r) {
      const size_t orow = (size_t)(b * S_LEN + q0 + wave * 16 + lgr * 4 + r);
      aob[(orow * NH + h) * HD + t * 16 + ln15] = f2bf(acc[t][r] * inv_l[r]);
    }
}

// ---------------------------------------------------------------------------
extern "C" void kernel_launch(void* const* d_in, const int* in_sizes, int n_in,
                              void* d_out, int out_size, void* d_ws, size_t ws_size,
                              hipStream_t stream) {
  const float* x    = (const float*)d_in[0];
  const float* cosb = (const float*)d_in[1];
  const float* sinb = (const float*)d_in[2];
  const float* Wq   = (const float*)d_in[3];
  const float* Wk   = (const float*)d_in[4];
  const float* Wv   = (const float*)d_in[5];
  const float* Wo   = (const float*)d_in[6];
  const float* qw   = (const float*)d_in[7];
  const float* kw   = (const float*)d_in[8];
  float* out = (float*)d_out;

  unsigned short* ws = (unsigned short*)d_ws;
  unsigned short* xb     = ws;                    // 8192*640  = 5242880
  unsigned short* Wqkvt  = xb + 5242880;          // 1536*640  = 983040
  unsigned short* Wot    = Wqkvt + 983040;        // 640*1024  = 655360
  unsigned short* qkvb   = Wot + 655360;          // 8192*1536 = 12582912
  unsigned short* vtb    = qkvb + 12582912;       // 8192*256  = 2097152
  unsigned short* aob    = vtb + 2097152;         // 8192*1024 = 8388608
  const int M = 2 * S_LEN;

  cvt_bf16_kernel<<<(M * 640 / 4 + 255) / 256, 256, 0, stream>>>(x, xb, M * 640 / 4);
  trcast64_kernel<<<dim3(1024 / 64, 640 / 64), 256, 0, stream>>>(Wq, Wqkvt, 640, 1024);
  trcast64_kernel<<<dim3(256 / 64, 640 / 64), 256, 0, stream>>>(Wk, Wqkvt + (size_t)1024 * 640, 640, 256);
  trcast64_kernel<<<dim3(256 / 64, 640 / 64), 256, 0, stream>>>(Wv, Wqkvt + (size_t)1280 * 640, 640, 256);
  trcast64_kernel<<<dim3(640 / 64, 1024 / 64), 256, 0, stream>>>(Wo, Wot, 1024, 640);
  gemm_bt<true><<<dim3(QKV_N / 128, M / 128), 256, 0, stream>>>(xb, Wqkvt, qkvb, M, QKV_N, 640);
  normrope_kernel<<<M * 5, 256, 0, stream>>>(qkvb, cosb, sinb, qw, kw);
  vtranspose_kernel<<<256, 256, 0, stream>>>(qkvb, vtb);
  attn_mfma_kernel<<<M / 64 * NH, 256, 0, stream>>>(qkvb, vtb, aob);
  gemm_bt<false><<<dim3(640 / 128, M / 128), 256, 0, stream>>>(aob, Wot, out, M, 640, 1024);
}

// Round 5
// 231.200 us; speedup vs baseline: 1.2067x; 1.2067x over previous
//
#include <hip/hip_runtime.h>
#include <hip/hip_bf16.h>

#define S_LEN 4096
#define NH 4
#define HD 256
#define WIN 512
#define ATT_SCALE 0.0625f   // 256^-0.5
#define QKV_N 1536          // packed q(1024) | k(256) | v(256)

typedef short s16x8 __attribute__((ext_vector_type(8)));
typedef float f32x4 __attribute__((ext_vector_type(4)));

static __device__ inline unsigned short f2bf(float f) {
  union { float f; unsigned int u; } v; v.f = f;
  unsigned int r = v.u + 0x7fff + ((v.u >> 16) & 1);   // RNE
  return (unsigned short)(r >> 16);
}
static __device__ inline float bf2f(unsigned short h) {
  union { unsigned int u; float f; } v; v.u = ((unsigned int)h) << 16;
  return v.f;
}
static __device__ inline void gl2lds16(const void* g, void* l) {
  __builtin_amdgcn_global_load_lds(
      (const __attribute__((address_space(1))) unsigned int*)g,
      (__attribute__((address_space(3))) unsigned int*)l, 16, 0, 0);
}

// ---------------------------------------------------------------------------
// x (fp32) -> bf16, packed uint2 stores. n4 = n/4.
// ---------------------------------------------------------------------------
__global__ __launch_bounds__(256) void cvt_bf16_kernel(const float* __restrict__ src,
                                                       unsigned short* __restrict__ dst,
                                                       int n4) {
  const int t = blockIdx.x * 256 + threadIdx.x;
  if (t >= n4) return;
  const float4 v = ((const float4*)src)[t];
  const unsigned int p0 = f2bf(v.x) | ((unsigned int)f2bf(v.y) << 16);
  const unsigned int p1 = f2bf(v.z) | ((unsigned int)f2bf(v.w) << 16);
  *(uint2*)(dst + (size_t)t * 4) = make_uint2(p0, p1);
}

// ---------------------------------------------------------------------------
// Transpose + cast: dst[n*K + k] = bf16(src[k*N + n]).  K,N multiples of 64.
// ---------------------------------------------------------------------------
__global__ __launch_bounds__(256) void trcast64_kernel(const float* __restrict__ src,
                                                       unsigned short* __restrict__ dst,
                                                       int K, int N) {
  __shared__ float ts[64][65];
  const int bn = blockIdx.x, bk = blockIdx.y;
  const int tid = threadIdx.x;
#pragma unroll
  for (int it = 0; it < 4; ++it) {
    const int c = it * 256 + tid;
    const int row = c >> 4, col4 = (c & 15) << 2;
    const float4 v = *(const float4*)(src + (size_t)(bk * 64 + row) * N + bn * 64 + col4);
    ts[row][col4 + 0] = v.x; ts[row][col4 + 1] = v.y;
    ts[row][col4 + 2] = v.z; ts[row][col4 + 3] = v.w;
  }
  __syncthreads();
#pragma unroll
  for (int it = 0; it < 4; ++it) {
    const int c = it * 256 + tid;
    const int nrow = c >> 4, kc4 = (c & 15) << 2;
    const unsigned int p0 = f2bf(ts[kc4 + 0][nrow]) | ((unsigned int)f2bf(ts[kc4 + 1][nrow]) << 16);
    const unsigned int p1 = f2bf(ts[kc4 + 2][nrow]) | ((unsigned int)f2bf(ts[kc4 + 3][nrow]) << 16);
    *(uint2*)(dst + (size_t)(bn * 64 + nrow) * K + bk * 64 + kc4) = make_uint2(p0, p1);
  }
}

// ---------------------------------------------------------------------------
// bf16 MFMA GEMM (m97 structure): C[M,N] = A[M,K] @ Bt[N,K]^T.
// ---------------------------------------------------------------------------
template <bool BF16OUT>
__global__ __launch_bounds__(256) void gemm_bt(const unsigned short* __restrict__ A,
                                               const unsigned short* __restrict__ Bt,
                                               void* __restrict__ Cv,
                                               int M, int N, int K) {
  __shared__ unsigned short As[128 * 32];
  __shared__ unsigned short Bs[128 * 32];
  const int tid = threadIdx.x;
  const int wave = tid >> 6, lane = tid & 63;
  const int ln15 = lane & 15, lgr = lane >> 4;
  const int bm = blockIdx.y, bn = blockIdx.x;
  const int wr = wave & 1, wc = wave >> 1;
  const unsigned short* Ab = A + (size_t)bm * 128 * K;
  const unsigned short* Bb = Bt + (size_t)bn * 128 * K;

  f32x4 acc[4][4];
#pragma unroll
  for (int mt = 0; mt < 4; ++mt)
#pragma unroll
    for (int nt = 0; nt < 4; ++nt) acc[mt][nt] = (f32x4){0.f, 0.f, 0.f, 0.f};

  for (int kt = 0; kt < K; kt += 32) {
#pragma unroll
    for (int i = 0; i < 2; ++i) {
      const int c = tid + 256 * i;
      const int row = c >> 2, kc = (c & 3) << 3;
      gl2lds16(Ab + (size_t)row * K + kt + kc, &As[c * 8]);
      gl2lds16(Bb + (size_t)row * K + kt + kc, &Bs[c * 8]);
    }
    __syncthreads();
    s16x8 af[4], bfr[4];
#pragma unroll
    for (int t = 0; t < 4; ++t) {
      af[t]  = *(const s16x8*)&As[(wr * 64 + t * 16 + ln15) * 32 + lgr * 8];
      bfr[t] = *(const s16x8*)&Bs[(wc * 64 + t * 16 + ln15) * 32 + lgr * 8];
    }
#pragma unroll
    for (int mt = 0; mt < 4; ++mt)
#pragma unroll
      for (int nt = 0; nt < 4; ++nt)
        acc[mt][nt] = __builtin_amdgcn_mfma_f32_16x16x32_bf16(af[mt], bfr[nt], acc[mt][nt], 0, 0, 0);
    __syncthreads();
  }

#pragma unroll
  for (int mt = 0; mt < 4; ++mt)
#pragma unroll
    for (int nt = 0; nt < 4; ++nt)
#pragma unroll
      for (int r = 0; r < 4; ++r) {
        const size_t row = bm * 128 + wr * 64 + mt * 16 + lgr * 4 + r;
        const size_t col = bn * 128 + wc * 64 + nt * 16 + ln15;
        if (BF16OUT) ((unsigned short*)Cv)[row * N + col] = f2bf(acc[mt][nt][r]);
        else         ((float*)Cv)[row * N + col] = acc[mt][nt][r];
      }
}

// ---------------------------------------------------------------------------
// Fused RMSNorm + RoPE, in place on packed bf16 qkv (row stride 1536).
// ---------------------------------------------------------------------------
__global__ __launch_bounds__(256) void normrope_kernel(
    unsigned short* __restrict__ qkv,
    const float* __restrict__ cosb, const float* __restrict__ sinb,
    const float* __restrict__ qw, const float* __restrict__ kw) {
  const int idx = blockIdx.x;
  const int h = idx % 5;
  const int bs = idx / 5;
  const int s = bs & (S_LEN - 1);
  unsigned short* base = qkv + (size_t)bs * QKV_N;
  unsigned short* row; const float* w; float oscale;
  if (h < 4) { row = base + h * HD;  w = qw; oscale = ATT_SCALE; }
  else       { row = base + 4 * HD;  w = kw; oscale = 1.0f; }
  const int tid = threadIdx.x;
  const int lane = tid & 63, wave = tid >> 6;
  __shared__ float xs[HD];
  __shared__ float red[4];
  const float xv = bf2f(row[tid]);
  xs[tid] = xv;
  float ssq = xv * xv;
#pragma unroll
  for (int off = 32; off > 0; off >>= 1) ssq += __shfl_xor(ssq, off);
  if (lane == 0) red[wave] = ssq;
  __syncthreads();
  const float tot = red[0] + red[1] + red[2] + red[3];
  const float inv = rsqrtf(tot * (1.0f / 256.0f) + 1e-6f);
  const int pi = tid >> 1;
  const float c = cosb[s * (HD / 2) + pi];
  const float sn = sinb[s * (HD / 2) + pi];
  const float a = xs[pi * 2]     * inv * (1.0f + w[pi * 2]);
  const float b = xs[pi * 2 + 1] * inv * (1.0f + w[pi * 2 + 1]);
  const float outv = ((tid & 1) ? (a * sn + b * c) : (a * c - b * sn)) * oscale;
  row[tid] = f2bf(outv);
}

// ---------------------------------------------------------------------------
// V transpose, tile-blocked: vtb[b][jt][d][jj] = v[b][jt*32+jj][d] (bf16)
// ---------------------------------------------------------------------------
__global__ __launch_bounds__(256) void vtranspose_kernel(
    const unsigned short* __restrict__ qkv, unsigned short* __restrict__ vtb) {
  __shared__ unsigned short ts[32][264];
  const int b = blockIdx.x >> 7, jt = blockIdx.x & 127;
  const int tid = threadIdx.x;
  const unsigned short* src = qkv + ((size_t)(b * S_LEN) + jt * 32) * QKV_N + 5 * HD;
#pragma unroll
  for (int it = 0; it < 4; ++it) {
    const int c = tid + 256 * it;
    const int row = c >> 5, col8 = (c & 31) << 3;
    *(uint4*)&ts[row][col8] = *(const uint4*)(src + (size_t)row * QKV_N + col8);
  }
  __syncthreads();
  unsigned short tmp[32];
#pragma unroll
  for (int jj = 0; jj < 32; ++jj) tmp[jj] = ts[jj][tid];
  unsigned short* dst = vtb + ((size_t)(b * 128 + jt) * 256 + tid) * 32;
#pragma unroll
  for (int wq = 0; wq < 4; ++wq) *(uint4*)(dst + wq * 8) = *(uint4*)(tmp + wq * 8);
}

// ---------------------------------------------------------------------------
// Flash-style sliding-window MQA, bf16 MFMA.
// - XCD swizzle: xcd = blockIdx&7 owns q-tiles [xcd*16,xcd*16+16) x 4 heads.
// - Static-max softmax (RMSNorm bounds |q.k|*scale <= 16): no online max.
// - Double-buffered K/V staging via global_load_lds (no staging VGPRs ->
//   no scratch spill, the R4 regression).
// - LDS in FRAGMENT ORDER: 1KB chunk per 16x32 MFMA strip, lane i <-> 16B at
//   chunk+16*i. Matches gl2lds's wave-uniform-base+lane*16 write pattern AND
//   makes all ds_read_b128 lane-contiguous (conflict-free).
// ---------------------------------------------------------------------------
#define PS_LD 40

__global__ __launch_bounds__(256) void attn_mfma_kernel(
    const unsigned short* __restrict__ qkv, const unsigned short* __restrict__ vtb,
    unsigned short* __restrict__ aob) {
  const int g = blockIdx.x;
  const int xcd = g & 7, slot = g >> 3;      // assume block j -> XCD j%8
  const int h = slot >> 4;                   // 0..3
  const int qt = xcd * 16 + (slot & 15);     // 0..127
  const int b = qt >> 6;
  const int q0 = (qt & 63) << 6;
  const int tid = threadIdx.x;
  const int wave = tid >> 6;
  const int lane = tid & 63;
  const int ln15 = lane & 15;
  const int lgr = lane >> 4;

  __shared__ unsigned short Ks[2][16 * 512];   // chunk c=ct*8+f: K rows ct*16..+15, cols f*32..+31
  __shared__ unsigned short Vts[2][16 * 512];  // chunk t: Vt rows t*16..+15 (d), cols 0..31 (jj)
  __shared__ unsigned short Ps[4][16 * PS_LD];

  const size_t qrow = (size_t)(b * S_LEN + q0 + wave * 16 + ln15) * QKV_N + h * HD;
  s16x8 qfrag[8];
#pragma unroll
  for (int f = 0; f < 8; ++f)
    qfrag[f] = *(const s16x8*)(qkv + qrow + f * 32 + lgr * 8);

  f32x4 acc[16];
#pragma unroll
  for (int t = 0; t < 16; ++t) acc[t] = (f32x4){0.f, 0.f, 0.f, 0.f};
  float l_part[4] = {0.f, 0.f, 0.f, 0.f};

  const int kt_lo = max(0, q0 - WIN) >> 5;
  const int kt_hi = (q0 + 63) >> 5;
  const unsigned short* kbase = qkv + (size_t)(b * S_LEN) * QKV_N + 4 * HD;
  const unsigned short* vbase = vtb + (size_t)b * (S_LEN / 32) * HD * 32;

  // Stage kt's K/V into buffer buf. Wave w owns chunks w*4..w*4+3 of each.
  // K chunk c (ct=c>>3, f=c&7): lane j -> global (row kt*32+ct*16+(j&15),
  //   cols f*32+(j>>4)*8 ..+7), LDS Ks[buf][c*512 + j*8].
  // V chunk c: lane j -> global Vt (d = c*16+(j&15), jj = (j>>4)*8..+7).
  auto stage = [&](int kt, int buf) {
#pragma unroll
    for (int u = 0; u < 4; ++u) {
      const int c = wave * 4 + u;
      const int ct = c >> 3, f = c & 7;
      const unsigned short* gk =
          kbase + (size_t)(kt * 32 + ct * 16 + ln15) * QKV_N + f * 32 + lgr * 8;
      gl2lds16(gk, &Ks[buf][c * 512]);
      const unsigned short* gv =
          vbase + (size_t)kt * (HD * 32) + (size_t)(c * 16 + ln15) * 32 + lgr * 8;
      gl2lds16(gv, &Vts[buf][c * 512]);
    }
  };

  stage(kt_lo, 0);
  __syncthreads();

  unsigned short* psw = Ps[wave];
  const int i_row0 = q0 + wave * 16 + lgr * 4;

  for (int kt = kt_lo; kt <= kt_hi; ++kt) {
    const int cur = (kt - kt_lo) & 1;
    if (kt < kt_hi) stage(kt + 1, cur ^ 1);   // async prefetch, no VGPR residency

    // QK^T: fragment reads are lane-contiguous (chunk + lane*16B)
    f32x4 sc[2];
    sc[0] = (f32x4){0.f, 0.f, 0.f, 0.f};
    sc[1] = (f32x4){0.f, 0.f, 0.f, 0.f};
#pragma unroll
    for (int f = 0; f < 8; ++f) {
#pragma unroll
      for (int ct = 0; ct < 2; ++ct) {
        const s16x8 kf = *(const s16x8*)&Ks[cur][(ct * 8 + f) * 512 + lane * 8];
        sc[ct] = __builtin_amdgcn_mfma_f32_16x16x32_bf16(qfrag[f], kf, sc[ct], 0, 0, 0);
      }
    }

    // static-max softmax: p = exp(s - 16), masked to 0
    const int j0 = kt * 32 + ln15;
    float p0[4], p1[4];
#pragma unroll
    for (int r = 0; r < 4; ++r) {
      const int i = i_row0 + r;
      const bool a0 = (j0 <= i) && (i - j0 <= WIN);
      const bool a1 = (j0 + 16 <= i) && (i - (j0 + 16) <= WIN);
      const float e0 = __expf(sc[0][r] - 16.0f);
      const float e1 = __expf(sc[1][r] - 16.0f);
      p0[r] = a0 ? e0 : 0.0f;
      p1[r] = a1 ? e1 : 0.0f;
      l_part[r] += p0[r] + p1[r];
    }
#pragma unroll
    for (int r = 0; r < 4; ++r) {
      psw[(lgr * 4 + r) * PS_LD + ln15]      = f2bf(p0[r]);
      psw[(lgr * 4 + r) * PS_LD + 16 + ln15] = f2bf(p1[r]);
    }
    // wave-private P: in-wave lgkmcnt ordering suffices, no barrier
    const s16x8 pf = *(const s16x8*)&psw[ln15 * PS_LD + lgr * 8];
#pragma unroll
    for (int t = 0; t < 16; ++t) {
      const s16x8 vf = *(const s16x8*)&Vts[cur][t * 512 + lane * 8];
      acc[t] = __builtin_amdgcn_mfma_f32_16x16x32_bf16(pf, vf, acc[t], 0, 0, 0);
    }
    __syncthreads();   // drains prefetch (issued a full compute-body ago)
  }

  // reduce l across the 16 lanes of each row group
#pragma unroll
  for (int off = 1; off < 16; off <<= 1)
#pragma unroll
    for (int r = 0; r < 4; ++r) l_part[r] += __shfl_xor(l_part[r], off);

  float inv_l[4];
#pragma unroll
  for (int r = 0; r < 4; ++r) inv_l[r] = 1.0f / l_part[r];
#pragma unroll
  for (int t = 0; t < 16; ++t)
#pragma unroll
    for (int r = 0; r < 4; ++r) {
      const size_t orow = (size_t)(b * S_LEN + q0 + wave * 16 + lgr * 4 + r);
      aob[(orow * NH + h) * HD + t * 16 + ln15] = f2bf(acc[t][r] * inv_l[r]);
    }
}

// ---------------------------------------------------------------------------
extern "C" void kernel_launch(void* const* d_in, const int* in_sizes, int n_in,
                              void* d_out, int out_size, void* d_ws, size_t ws_size,
                              hipStream_t stream) {
  const float* x    = (const float*)d_in[0];
  const float* cosb = (const float*)d_in[1];
  const float* sinb = (const float*)d_in[2];
  const float* Wq   = (const float*)d_in[3];
  const float* Wk   = (const float*)d_in[4];
  const float* Wv   = (const float*)d_in[5];
  const float* Wo   = (const float*)d_in[6];
  const float* qw   = (const float*)d_in[7];
  const float* kw   = (const float*)d_in[8];
  float* out = (float*)d_out;

  unsigned short* ws = (unsigned short*)d_ws;
  unsigned short* xb     = ws;                    // 8192*640  = 5242880
  unsigned short* Wqkvt  = xb + 5242880;          // 1536*640  = 983040
  unsigned short* Wot    = Wqkvt + 983040;        // 640*1024  = 655360
  unsigned short* qkvb   = Wot + 655360;          // 8192*1536 = 12582912
  unsigned short* vtb    = qkvb + 12582912;       // 8192*256  = 2097152
  unsigned short* aob    = vtb + 2097152;         // 8192*1024 = 8388608
  const int M = 2 * S_LEN;

  cvt_bf16_kernel<<<(M * 640 / 4 + 255) / 256, 256, 0, stream>>>(x, xb, M * 640 / 4);
  trcast64_kernel<<<dim3(1024 / 64, 640 / 64), 256, 0, stream>>>(Wq, Wqkvt, 640, 1024);
  trcast64_kernel<<<dim3(256 / 64, 640 / 64), 256, 0, stream>>>(Wk, Wqkvt + (size_t)1024 * 640, 640, 256);
  trcast64_kernel<<<dim3(256 / 64, 640 / 64), 256, 0, stream>>>(Wv, Wqkvt + (size_t)1280 * 640, 640, 256);
  trcast64_kernel<<<dim3(640 / 64, 1024 / 64), 256, 0, stream>>>(Wo, Wot, 1024, 640);
  gemm_bt<true><<<dim3(QKV_N / 128, M / 128), 256, 0, stream>>>(xb, Wqkvt, qkvb, M, QKV_N, 640);
  normrope_kernel<<<M * 5, 256, 0, stream>>>(qkvb, cosb, sinb, qw, kw);
  vtranspose_kernel<<<256, 256, 0, stream>>>(qkvb, vtb);
  attn_mfma_kernel<<<M / 64 * NH, 256, 0, stream>>>(qkvb, vtb, aob);
  gemm_bt<false><<<dim3(640 / 128, M / 128), 256, 0, stream>>>(aob, Wot, out, M, 640, 1024);
}

// Round 6
// 215.391 us; speedup vs baseline: 1.2953x; 1.0734x over previous
//
#include <hip/hip_runtime.h>
#include <hip/hip_bf16.h>

#define S_LEN 4096
#define NH 4
#define HD 256
#define WIN 512
#define ATT_SCALE 0.0625f   // 256^-0.5
#define QKV_N 1536          // packed q(1024) | k(256) | v(256)

typedef short s16x8 __attribute__((ext_vector_type(8)));
typedef float f32x4 __attribute__((ext_vector_type(4)));

static __device__ inline unsigned short f2bf(float f) {
  union { float f; unsigned int u; } v; v.f = f;
  unsigned int r = v.u + 0x7fff + ((v.u >> 16) & 1);   // RNE
  return (unsigned short)(r >> 16);
}
static __device__ inline float bf2f(unsigned short h) {
  union { unsigned int u; float f; } v; v.u = ((unsigned int)h) << 16;
  return v.f;
}
static __device__ inline void gl2lds16(const void* g, void* l) {
  __builtin_amdgcn_global_load_lds(
      (const __attribute__((address_space(1))) unsigned int*)g,
      (__attribute__((address_space(3))) unsigned int*)l, 16, 0, 0);
}

// ---------------------------------------------------------------------------
// Fused prep: region [0,5120) = x fp32->bf16 cast; then 4 transpose+cast
// weight regions (Wq,Wk,Wv -> packed Wqkvt; Wo -> Wot). One dispatch.
// ---------------------------------------------------------------------------
static __device__ void trcast_tile(const float* __restrict__ src,
                                   unsigned short* __restrict__ dst,
                                   int K, int N, int bn, int bk, int tid,
                                   float* ts /*[64][65]*/) {
#pragma unroll
  for (int it = 0; it < 4; ++it) {
    const int c = it * 256 + tid;
    const int row = c >> 4, col4 = (c & 15) << 2;
    const float4 v = *(const float4*)(src + (size_t)(bk * 64 + row) * N + bn * 64 + col4);
    ts[row * 65 + col4 + 0] = v.x; ts[row * 65 + col4 + 1] = v.y;
    ts[row * 65 + col4 + 2] = v.z; ts[row * 65 + col4 + 3] = v.w;
  }
  __syncthreads();
#pragma unroll
  for (int it = 0; it < 4; ++it) {
    const int c = it * 256 + tid;
    const int nrow = c >> 4, kc4 = (c & 15) << 2;
    const unsigned int p0 = f2bf(ts[(kc4 + 0) * 65 + nrow]) | ((unsigned int)f2bf(ts[(kc4 + 1) * 65 + nrow]) << 16);
    const unsigned int p1 = f2bf(ts[(kc4 + 2) * 65 + nrow]) | ((unsigned int)f2bf(ts[(kc4 + 3) * 65 + nrow]) << 16);
    *(uint2*)(dst + (size_t)(bn * 64 + nrow) * K + bk * 64 + kc4) = make_uint2(p0, p1);
  }
}

__global__ __launch_bounds__(256) void prep_kernel(
    const float* __restrict__ x, unsigned short* __restrict__ xb,
    const float* __restrict__ Wq, const float* __restrict__ Wk,
    const float* __restrict__ Wv, const float* __restrict__ Wo,
    unsigned short* __restrict__ Wqkvt, unsigned short* __restrict__ Wot) {
  __shared__ float ts[64 * 65];
  const int g = blockIdx.x;
  const int tid = threadIdx.x;
  if (g < 5120) {                    // cvt x -> bf16 (1310720 float4 elems)
    const int t = g * 256 + tid;
    const float4 v = ((const float4*)x)[t];
    const unsigned int p0 = f2bf(v.x) | ((unsigned int)f2bf(v.y) << 16);
    const unsigned int p1 = f2bf(v.z) | ((unsigned int)f2bf(v.w) << 16);
    *(uint2*)(xb + (size_t)t * 4) = make_uint2(p0, p1);
  } else if (g < 5280) {             // Wq: N=1024 (16), K=640 (10)
    const int g2 = g - 5120;
    trcast_tile(Wq, Wqkvt, 640, 1024, g2 & 15, g2 >> 4, tid, ts);
  } else if (g < 5320) {             // Wk: N=256 (4), K=640 (10)
    const int g2 = g - 5280;
    trcast_tile(Wk, Wqkvt + (size_t)1024 * 640, 640, 256, g2 & 3, g2 >> 2, tid, ts);
  } else if (g < 5360) {             // Wv
    const int g2 = g - 5320;
    trcast_tile(Wv, Wqkvt + (size_t)1280 * 640, 640, 256, g2 & 3, g2 >> 2, tid, ts);
  } else {                           // Wo: N=640 (10), K=1024 (16)
    const int g2 = g - 5360;
    trcast_tile(Wo, Wot, 1024, 640, g2 % 10, g2 / 10, tid, ts);
  }
}

// ---------------------------------------------------------------------------
// bf16 MFMA GEMM (m97 structure): C[M,N] = A[M,K] @ Bt[N,K]^T. 128x128 tile.
// ---------------------------------------------------------------------------
template <bool BF16OUT>
__global__ __launch_bounds__(256) void gemm_bt(const unsigned short* __restrict__ A,
                                               const unsigned short* __restrict__ Bt,
                                               void* __restrict__ Cv,
                                               int M, int N, int K) {
  __shared__ unsigned short As[128 * 32];
  __shared__ unsigned short Bs[128 * 32];
  const int tid = threadIdx.x;
  const int wave = tid >> 6, lane = tid & 63;
  const int ln15 = lane & 15, lgr = lane >> 4;
  const int bm = blockIdx.y, bn = blockIdx.x;
  const int wr = wave & 1, wc = wave >> 1;
  const unsigned short* Ab = A + (size_t)bm * 128 * K;
  const unsigned short* Bb = Bt + (size_t)bn * 128 * K;

  f32x4 acc[4][4];
#pragma unroll
  for (int mt = 0; mt < 4; ++mt)
#pragma unroll
    for (int nt = 0; nt < 4; ++nt) acc[mt][nt] = (f32x4){0.f, 0.f, 0.f, 0.f};

  for (int kt = 0; kt < K; kt += 32) {
#pragma unroll
    for (int i = 0; i < 2; ++i) {
      const int c = tid + 256 * i;
      const int row = c >> 2, kc = (c & 3) << 3;
      gl2lds16(Ab + (size_t)row * K + kt + kc, &As[c * 8]);
      gl2lds16(Bb + (size_t)row * K + kt + kc, &Bs[c * 8]);
    }
    __syncthreads();
    s16x8 af[4], bfr[4];
#pragma unroll
    for (int t = 0; t < 4; ++t) {
      af[t]  = *(const s16x8*)&As[(wr * 64 + t * 16 + ln15) * 32 + lgr * 8];
      bfr[t] = *(const s16x8*)&Bs[(wc * 64 + t * 16 + ln15) * 32 + lgr * 8];
    }
#pragma unroll
    for (int mt = 0; mt < 4; ++mt)
#pragma unroll
      for (int nt = 0; nt < 4; ++nt)
        acc[mt][nt] = __builtin_amdgcn_mfma_f32_16x16x32_bf16(af[mt], bfr[nt], acc[mt][nt], 0, 0, 0);
    __syncthreads();
  }

#pragma unroll
  for (int mt = 0; mt < 4; ++mt)
#pragma unroll
    for (int nt = 0; nt < 4; ++nt)
#pragma unroll
      for (int r = 0; r < 4; ++r) {
        const size_t row = bm * 128 + wr * 64 + mt * 16 + lgr * 4 + r;
        const size_t col = bn * 128 + wc * 64 + nt * 16 + ln15;
        if (BF16OUT) ((unsigned short*)Cv)[row * N + col] = f2bf(acc[mt][nt][r]);
        else         ((float*)Cv)[row * N + col] = acc[mt][nt][r];
      }
}

// ---------------------------------------------------------------------------
// 64x128-tile variant (fp32 out) for the output projection: N=640 -> 5 n-tiles,
// grid 128x5 = 640 blocks (2.5/CU vs 1.25/CU at 128x128 -> smaller tail).
// Wave wc owns 32 n-cols; acc 4x2 per wave.
// ---------------------------------------------------------------------------
__global__ __launch_bounds__(256) void gemm_bt64(const unsigned short* __restrict__ A,
                                                 const unsigned short* __restrict__ Bt,
                                                 float* __restrict__ C,
                                                 int M, int N, int K) {
  __shared__ unsigned short As[64 * 32];
  __shared__ unsigned short Bs[128 * 32];
  const int tid = threadIdx.x;
  const int wave = tid >> 6, lane = tid & 63;
  const int ln15 = lane & 15, lgr = lane >> 4;
  const int bm = blockIdx.y, bn = blockIdx.x;
  const unsigned short* Ab = A + (size_t)bm * 64 * K;
  const unsigned short* Bb = Bt + (size_t)bn * 128 * K;

  f32x4 acc[4][2];
#pragma unroll
  for (int mt = 0; mt < 4; ++mt)
#pragma unroll
    for (int nt = 0; nt < 2; ++nt) acc[mt][nt] = (f32x4){0.f, 0.f, 0.f, 0.f};

  for (int kt = 0; kt < K; kt += 32) {
    {
      const int row = tid >> 2, kc = (tid & 3) << 3;
      gl2lds16(Ab + (size_t)row * K + kt + kc, &As[tid * 8]);
#pragma unroll
      for (int i = 0; i < 2; ++i) {
        const int c = tid + 256 * i;
        const int brow = c >> 2, bkc = (c & 3) << 3;
        gl2lds16(Bb + (size_t)brow * K + kt + bkc, &Bs[c * 8]);
      }
    }
    __syncthreads();
    s16x8 af[4], bfr[2];
#pragma unroll
    for (int t = 0; t < 4; ++t)
      af[t] = *(const s16x8*)&As[(t * 16 + ln15) * 32 + lgr * 8];
#pragma unroll
    for (int t = 0; t < 2; ++t)
      bfr[t] = *(const s16x8*)&Bs[(wave * 32 + t * 16 + ln15) * 32 + lgr * 8];
#pragma unroll
    for (int mt = 0; mt < 4; ++mt)
#pragma unroll
      for (int nt = 0; nt < 2; ++nt)
        acc[mt][nt] = __builtin_amdgcn_mfma_f32_16x16x32_bf16(af[mt], bfr[nt], acc[mt][nt], 0, 0, 0);
    __syncthreads();
  }

#pragma unroll
  for (int mt = 0; mt < 4; ++mt)
#pragma unroll
    for (int nt = 0; nt < 2; ++nt)
#pragma unroll
      for (int r = 0; r < 4; ++r) {
        const size_t row = bm * 64 + mt * 16 + lgr * 4 + r;
        const size_t col = bn * 128 + wave * 32 + nt * 16 + ln15;
        C[row * N + col] = acc[mt][nt][r];
      }
}

// ---------------------------------------------------------------------------
// Fused RMSNorm+RoPE (blocks [0,40960)) + V-transpose (blocks [40960,41216)).
// V-transpose uses INTERLEAVED key storage order s = 2*(jj&15) | (jj>>4), so
// attention's P round-trip can write packed b32 pairs (PV is key-permutation
// invariant as long as P cols and Vt cols share the order).
// ---------------------------------------------------------------------------
__global__ __launch_bounds__(256) void normrope_vt_kernel(
    unsigned short* __restrict__ qkv,
    const float* __restrict__ cosb, const float* __restrict__ sinb,
    const float* __restrict__ qw, const float* __restrict__ kw,
    unsigned short* __restrict__ vtb) {
  const int idx = blockIdx.x;
  const int tid = threadIdx.x;
  if (idx < 40960) {
    const int h = idx % 5;
    const int bs = idx / 5;
    const int s = bs & (S_LEN - 1);
    unsigned short* base = qkv + (size_t)bs * QKV_N;
    unsigned short* row; const float* w; float oscale;
    if (h < 4) { row = base + h * HD;  w = qw; oscale = ATT_SCALE; }
    else       { row = base + 4 * HD;  w = kw; oscale = 1.0f; }
    const int lane = tid & 63, wave = tid >> 6;
    __shared__ float xs[HD];
    __shared__ float red[4];
    const float xv = bf2f(row[tid]);
    xs[tid] = xv;
    float ssq = xv * xv;
#pragma unroll
    for (int off = 32; off > 0; off >>= 1) ssq += __shfl_xor(ssq, off);
    if (lane == 0) red[wave] = ssq;
    __syncthreads();
    const float tot = red[0] + red[1] + red[2] + red[3];
    const float inv = rsqrtf(tot * (1.0f / 256.0f) + 1e-6f);
    const int pi = tid >> 1;
    const float c = cosb[s * (HD / 2) + pi];
    const float sn = sinb[s * (HD / 2) + pi];
    const float a = xs[pi * 2]     * inv * (1.0f + w[pi * 2]);
    const float b = xs[pi * 2 + 1] * inv * (1.0f + w[pi * 2 + 1]);
    const float outv = ((tid & 1) ? (a * sn + b * c) : (a * c - b * sn)) * oscale;
    row[tid] = f2bf(outv);
  } else {
    __shared__ unsigned short ts[32][264];
    const int g2 = idx - 40960;
    const int b = g2 >> 7, jt = g2 & 127;
    const unsigned short* src = qkv + ((size_t)(b * S_LEN) + jt * 32) * QKV_N + 5 * HD;
#pragma unroll
    for (int it = 0; it < 4; ++it) {
      const int c = tid + 256 * it;
      const int row = c >> 5, col8 = (c & 31) << 3;
      *(uint4*)&ts[row][col8] = *(const uint4*)(src + (size_t)row * QKV_N + col8);
    }
    __syncthreads();
    unsigned short tmp[32];
#pragma unroll
    for (int s2 = 0; s2 < 32; ++s2) {
      const int jj = (s2 >> 1) | ((s2 & 1) << 4);   // inverse of s = 2*(jj&15)|(jj>>4)
      tmp[s2] = ts[jj][tid];
    }
    unsigned short* dst = vtb + ((size_t)(b * 128 + jt) * 256 + tid) * 32;
#pragma unroll
    for (int wq = 0; wq < 4; ++wq) *(uint4*)(dst + wq * 8) = *(uint4*)(tmp + wq * 8);
  }
}

// ---------------------------------------------------------------------------
// Flash-style sliding-window MQA, bf16 MFMA.
// - XCD swizzle, static-max softmax, gl2lds double-buffer, fragment-order LDS.
// - P written as packed b32 pairs (interleaved key order matching vtb).
// ---------------------------------------------------------------------------
#define PS_LD 40

__global__ __launch_bounds__(256) void attn_mfma_kernel(
    const unsigned short* __restrict__ qkv, const unsigned short* __restrict__ vtb,
    unsigned short* __restrict__ aob) {
  const int g = blockIdx.x;
  const int xcd = g & 7, slot = g >> 3;      // assume block j -> XCD j%8
  const int h = slot >> 4;                   // 0..3
  const int qt = xcd * 16 + (slot & 15);     // 0..127
  const int b = qt >> 6;
  const int q0 = (qt & 63) << 6;
  const int tid = threadIdx.x;
  const int wave = tid >> 6;
  const int lane = tid & 63;
  const int ln15 = lane & 15;
  const int lgr = lane >> 4;

  __shared__ unsigned short Ks[2][16 * 512];
  __shared__ unsigned short Vts[2][16 * 512];
  __shared__ unsigned short Ps[4][16 * PS_LD];

  const size_t qrow = (size_t)(b * S_LEN + q0 + wave * 16 + ln15) * QKV_N + h * HD;
  s16x8 qfrag[8];
#pragma unroll
  for (int f = 0; f < 8; ++f)
    qfrag[f] = *(const s16x8*)(qkv + qrow + f * 32 + lgr * 8);

  f32x4 acc[16];
#pragma unroll
  for (int t = 0; t < 16; ++t) acc[t] = (f32x4){0.f, 0.f, 0.f, 0.f};
  float l_part[4] = {0.f, 0.f, 0.f, 0.f};

  const int kt_lo = max(0, q0 - WIN) >> 5;
  const int kt_hi = (q0 + 63) >> 5;
  const unsigned short* kbase = qkv + (size_t)(b * S_LEN) * QKV_N + 4 * HD;
  const unsigned short* vbase = vtb + (size_t)b * (S_LEN / 32) * HD * 32;

  auto stage = [&](int kt, int buf) {
#pragma unroll
    for (int u = 0; u < 4; ++u) {
      const int c = wave * 4 + u;
      const int ct = c >> 3, f = c & 7;
      const unsigned short* gk =
          kbase + (size_t)(kt * 32 + ct * 16 + ln15) * QKV_N + f * 32 + lgr * 8;
      gl2lds16(gk, &Ks[buf][c * 512]);
      const unsigned short* gv =
          vbase + (size_t)kt * (HD * 32) + (size_t)(c * 16 + ln15) * 32 + lgr * 8;
      gl2lds16(gv, &Vts[buf][c * 512]);
    }
  };

  stage(kt_lo, 0);
  __syncthreads();

  unsigned short* psw = Ps[wave];
  const int i_row0 = q0 + wave * 16 + lgr * 4;

  for (int kt = kt_lo; kt <= kt_hi; ++kt) {
    const int cur = (kt - kt_lo) & 1;
    if (kt < kt_hi) stage(kt + 1, cur ^ 1);

    // QK^T
    f32x4 sc[2];
    sc[0] = (f32x4){0.f, 0.f, 0.f, 0.f};
    sc[1] = (f32x4){0.f, 0.f, 0.f, 0.f};
#pragma unroll
    for (int f = 0; f < 8; ++f) {
#pragma unroll
      for (int ct = 0; ct < 2; ++ct) {
        const s16x8 kf = *(const s16x8*)&Ks[cur][(ct * 8 + f) * 512 + lane * 8];
        sc[ct] = __builtin_amdgcn_mfma_f32_16x16x32_bf16(qfrag[f], kf, sc[ct], 0, 0, 0);
      }
    }

    // static-max softmax: p = exp(s - 16), masked to 0
    const int j0 = kt * 32 + ln15;
    float p0[4], p1[4];
#pragma unroll
    for (int r = 0; r < 4; ++r) {
      const int i = i_row0 + r;
      const bool a0 = (j0 <= i) && (i - j0 <= WIN);
      const bool a1 = (j0 + 16 <= i) && (i - (j0 + 16) <= WIN);
      const float e0 = __expf(sc[0][r] - 16.0f);
      const float e1 = __expf(sc[1][r] - 16.0f);
      p0[r] = a0 ? e0 : 0.0f;
      p1[r] = a1 ? e1 : 0.0f;
      l_part[r] += p0[r] + p1[r];
    }
    // packed b32 P writes: col 2*ln15 = key ln15 (ct0), col 2*ln15+1 = key 16+ln15
#pragma unroll
    for (int r = 0; r < 4; ++r) {
      const unsigned int pk = (unsigned int)f2bf(p0[r]) | ((unsigned int)f2bf(p1[r]) << 16);
      *(unsigned int*)&psw[(lgr * 4 + r) * PS_LD + (ln15 << 1)] = pk;
    }
    const s16x8 pf = *(const s16x8*)&psw[ln15 * PS_LD + lgr * 8];
#pragma unroll
    for (int t = 0; t < 16; ++t) {
      const s16x8 vf = *(const s16x8*)&Vts[cur][t * 512 + lane * 8];
      acc[t] = __builtin_amdgcn_mfma_f32_16x16x32_bf16(pf, vf, acc[t], 0, 0, 0);
    }
    __syncthreads();
  }

#pragma unroll
  for (int off = 1; off < 16; off <<= 1)
#pragma unroll
    for (int r = 0; r < 4; ++r) l_part[r] += __shfl_xor(l_part[r], off);

  float inv_l[4];
#pragma unroll
  for (int r = 0; r < 4; ++r) inv_l[r] = 1.0f / l_part[r];
#pragma unroll
  for (int t = 0; t < 16; ++t)
#pragma unroll
    for (int r = 0; r < 4; ++r) {
      const size_t orow = (size_t)(b * S_LEN + q0 + wave * 16 + lgr * 4 + r);
      aob[(orow * NH + h) * HD + t * 16 + ln15] = f2bf(acc[t][r] * inv_l[r]);
    }
}

// ---------------------------------------------------------------------------
extern "C" void kernel_launch(void* const* d_in, const int* in_sizes, int n_in,
                              void* d_out, int out_size, void* d_ws, size_t ws_size,
                              hipStream_t stream) {
  const float* x    = (const float*)d_in[0];
  const float* cosb = (const float*)d_in[1];
  const float* sinb = (const float*)d_in[2];
  const float* Wq   = (const float*)d_in[3];
  const float* Wk   = (const float*)d_in[4];
  const float* Wv   = (const float*)d_in[5];
  const float* Wo   = (const float*)d_in[6];
  const float* qw   = (const float*)d_in[7];
  const float* kw   = (const float*)d_in[8];
  float* out = (float*)d_out;

  unsigned short* ws = (unsigned short*)d_ws;
  unsigned short* xb     = ws;                    // 8192*640  = 5242880
  unsigned short* Wqkvt  = xb + 5242880;          // 1536*640  = 983040
  unsigned short* Wot    = Wqkvt + 983040;        // 640*1024  = 655360
  unsigned short* qkvb   = Wot + 655360;          // 8192*1536 = 12582912
  unsigned short* vtb    = qkvb + 12582912;       // 8192*256  = 2097152
  unsigned short* aob    = vtb + 2097152;         // 8192*1024 = 8388608
  const int M = 2 * S_LEN;

  prep_kernel<<<5520, 256, 0, stream>>>(x, xb, Wq, Wk, Wv, Wo, Wqkvt, Wot);
  gemm_bt<true><<<dim3(QKV_N / 128, M / 128), 256, 0, stream>>>(xb, Wqkvt, qkvb, M, QKV_N, 640);
  normrope_vt_kernel<<<M * 5 + 256, 256, 0, stream>>>(qkvb, cosb, sinb, qw, kw, vtb);
  attn_mfma_kernel<<<M / 64 * NH, 256, 0, stream>>>(qkvb, vtb, aob);
  gemm_bt64<<<dim3(640 / 128, M / 64), 256, 0, stream>>>(aob, Wot, out, M, 640, 1024);
}